// Round 1
// baseline (88.817 us; speedup 1.0000x reference)
//
#include <hip/hip_runtime.h>
#include <math.h>

#define B_ 16
#define C_ 2048
#define Q_ 128
#define H_ 128
#define NEGV (-1000000000.0f)

// ws layout (floats):
//   sq   : [B][Q]      offset 0        (2048)
//   maxq : [B][C]      offset 2048     (32768)
//   mz   : [B][2]      offset 34816    (32)
//   q2c  : [B][H]      offset 34848    (2048)

__device__ __forceinline__ float wave_reduce_max(float v) {
#pragma unroll
  for (int off = 32; off; off >>= 1) v = fmaxf(v, __shfl_xor(v, off, 64));
  return v;
}
__device__ __forceinline__ float wave_reduce_sum(float v) {
#pragma unroll
  for (int off = 32; off; off >>= 1) v += __shfl_xor(v, off, 64);
  return v;
}

// K0: s_q[b,q] = query[b,q,:] . W[H:2H]
__global__ void k0_sq(const float* __restrict__ qry, const float* __restrict__ W,
                      float* __restrict__ sq) {
  int t = blockIdx.x * 256 + threadIdx.x;  // 2048 total
  if (t >= B_ * Q_) return;
  const float4* qp = (const float4*)(qry + (size_t)t * H_);
  const float4* wq = (const float4*)(W + H_);
  float s = 0.f;
#pragma unroll
  for (int j = 0; j < H_ / 4; j++) {
    float4 a = qp[j], w = wq[j];
    s += a.x * w.x + a.y * w.y + a.z * w.z + a.w * w.w;
  }
  sq[t] = s;
}

// K1: per (b, 64-c tile): S, softmax, c2q, G chunks 1-3, max_q.
// 512 threads = 8 waves, 8 c-rows per wave.
// query[b] staged in LDS, XOR-swizzled in 16B chunks: element (q,h) at
//   Qs[q*128 + (((h>>2) ^ (q&7))<<2) + (h&3)]
__global__ __launch_bounds__(512) void k1_main(
    const float* __restrict__ ctx, const float* __restrict__ qry,
    const float* __restrict__ W, const int* __restrict__ cmask,
    const int* __restrict__ qmask, const float* __restrict__ sq,
    float* __restrict__ out, float* __restrict__ maxq) {
  __shared__ float Qs[Q_ * H_];       // 64 KiB
  __shared__ float sqv[Q_];
  __shared__ float qmv[Q_];           // 1 = valid, 0 = masked
  __shared__ float xb[8][8 * H_];     // 32 KiB: per-wave x = ctx*w_cq rows
  __shared__ float ab[8][8 * H_];     // 32 KiB: per-wave softmax rows

  int b = blockIdx.x >> 5;
  int ct = blockIdx.x & 31;
  int tid = threadIdx.x;

  {  // stage query[b], swizzled
    const float4* qp = (const float4*)(qry + (size_t)b * Q_ * H_);
#pragma unroll
    for (int k = 0; k < 8; k++) {
      int i = tid + k * 512;          // 4096 float4 chunks
      float4 v = qp[i];
      int q = i >> 5, h4 = i & 31;
      *(float4*)&Qs[q * H_ + ((h4 ^ (q & 7)) << 2)] = v;
    }
  }
  if (tid < Q_) {
    sqv[tid] = sq[b * Q_ + tid];
    qmv[tid] = (qmask[b * Q_ + tid] != 0) ? 1.f : 0.f;
  }
  __syncthreads();

  int w = tid >> 6, l = tid & 63;
  int c0 = ct * 64 + w * 8;
  const float* ctxb = ctx + ((size_t)b * C_ + c0) * H_;

  float2 wc2 = *(const float2*)&W[2 * l];
  float2 wcq2 = *(const float2*)&W[2 * H_ + 2 * l];

  float2 cv[8];
  float sc[8];
#pragma unroll
  for (int i = 0; i < 8; i++) {
    float2 v = *(const float2*)&ctxb[i * H_ + 2 * l];
    cv[i] = v;
    *(float2*)&xb[w][i * H_ + 2 * l] = make_float2(v.x * wcq2.x, v.y * wcq2.y);
    sc[i] = wave_reduce_sum(v.x * wc2.x + v.y * wc2.y);
  }
  __builtin_amdgcn_wave_barrier();  // per-wave LDS write->read ordering

  // s_cq: lanes cover q (q0 = l, q1 = l+64); register tile 8c x 2q
  float s0[8], s1[8];
#pragma unroll
  for (int i = 0; i < 8; i++) { s0[i] = 0.f; s1[i] = 0.f; }
  int q0 = l, q1 = l + 64;
  int sw = l & 7;  // (q0&7) == (q1&7)
#pragma unroll 4
  for (int h4 = 0; h4 < 32; h4++) {
    float4 qv0 = *(const float4*)&Qs[q0 * H_ + ((h4 ^ sw) << 2)];
    float4 qv1 = *(const float4*)&Qs[q1 * H_ + ((h4 ^ sw) << 2)];
#pragma unroll
    for (int i = 0; i < 8; i++) {
      float4 xv = *(const float4*)&xb[w][i * H_ + h4 * 4];
      s0[i] += xv.x * qv0.x + xv.y * qv0.y + xv.z * qv0.z + xv.w * qv0.w;
      s1[i] += xv.x * qv1.x + xv.y * qv1.y + xv.z * qv1.z + xv.w * qv1.w;
    }
  }

  float sq0 = sqv[q0], sq1 = sqv[q1];
  float m0 = qmv[q0], m1 = qmv[q1];

#pragma unroll
  for (int i = 0; i < 8; i++) {
    float S0 = (m0 != 0.f) ? (sc[i] + sq0 + s0[i]) : NEGV;
    float S1 = (m1 != 0.f) ? (sc[i] + sq1 + s1[i]) : NEGV;
    float M = wave_reduce_max(fmaxf(S0, S1));
    float e0 = __expf(S0 - M), e1 = __expf(S1 - M);
    float Z = wave_reduce_sum(e0 + e1);
    float rz = 1.f / Z;
    ab[w][i * H_ + q0] = e0 * rz;
    ab[w][i * H_ + q1] = e1 * rz;
    if (l == 0) {
      int c = c0 + i;
      maxq[b * C_ + c] = (cmask[b * C_ + c] != 0) ? M : NEGV;
    }
  }
  __builtin_amdgcn_wave_barrier();

  // c2q: lanes cover h (h0 = 2l, h0+1); register tile 8c x 2h
  float2 o[8];
#pragma unroll
  for (int i = 0; i < 8; i++) o[i] = make_float2(0.f, 0.f);
  int hc = l >> 1;        // 16B chunk of h0
  int ho = (2 * l) & 3;   // offset within chunk (0 or 2)
#pragma unroll 2
  for (int q4 = 0; q4 < 32; q4++) {
    float2 qv[4];
#pragma unroll
    for (int j = 0; j < 4; j++) {
      int q = q4 * 4 + j;
      qv[j] = *(const float2*)&Qs[q * H_ + ((hc ^ (q & 7)) << 2) + ho];
    }
#pragma unroll
    for (int i = 0; i < 8; i++) {
      float4 av = *(const float4*)&ab[w][i * H_ + q4 * 4];
      o[i].x += av.x * qv[0].x + av.y * qv[1].x + av.z * qv[2].x + av.w * qv[3].x;
      o[i].y += av.x * qv[0].y + av.y * qv[1].y + av.z * qv[2].y + av.w * qv[3].y;
    }
  }

  // epilogue: G chunks 1-3
#pragma unroll
  for (int i = 0; i < 8; i++) {
    size_t base = ((size_t)(b * C_ + c0 + i)) * (4 * H_);
    *(float2*)&out[base + 2 * l] = cv[i];
    *(float2*)&out[base + H_ + 2 * l] = o[i];
    *(float2*)&out[base + 2 * H_ + 2 * l] =
        make_float2(cv[i].x * o[i].x, cv[i].y * o[i].y);
  }
}

// K2: per-b M/Z over maxq; zero q2c
__global__ void k2_mz(const float* __restrict__ maxq, float* __restrict__ mz,
                      float* __restrict__ q2c) {
  int b = blockIdx.x;
  int tid = threadIdx.x;  // 256
  __shared__ float red[256];
  float m = -INFINITY;
  for (int c = tid; c < C_; c += 256) m = fmaxf(m, maxq[b * C_ + c]);
  red[tid] = m;
  __syncthreads();
  for (int s = 128; s; s >>= 1) {
    if (tid < s) red[tid] = fmaxf(red[tid], red[tid + s]);
    __syncthreads();
  }
  float M = red[0];
  __syncthreads();
  float z = 0.f;
  for (int c = tid; c < C_; c += 256) z += __expf(maxq[b * C_ + c] - M);
  red[tid] = z;
  __syncthreads();
  for (int s = 128; s; s >>= 1) {
    if (tid < s) red[tid] += red[tid + s];
    __syncthreads();
  }
  if (tid == 0) {
    mz[b * 2] = M;
    mz[b * 2 + 1] = red[0];
  }
  if (tid < H_) q2c[b * H_ + tid] = 0.f;
}

// K3: q2c[b,h] += sum_{c in chunk} softmax_c(maxq)[c] * ctx[b,c,h]
__global__ void k3_q2c(const float* __restrict__ ctx,
                       const float* __restrict__ maxq,
                       const float* __restrict__ mz, float* __restrict__ q2c) {
  int b = blockIdx.x >> 4;
  int chunk = blockIdx.x & 15;
  int h = threadIdx.x;  // 128
  float M = mz[b * 2], Z = mz[b * 2 + 1];
  float acc = 0.f;
  int cbase = chunk * 128;
  for (int cc = 0; cc < 128; cc++) {
    int c = cbase + cc;
    float wgt = __expf(maxq[b * C_ + c] - M);
    acc += wgt * ctx[((size_t)b * C_ + c) * H_ + h];
  }
  atomicAdd(&q2c[b * H_ + h], acc / Z);
}

// K4: G chunk 4 = ctx * q2c (broadcast over c)
__global__ void k4_out(const float* __restrict__ ctx,
                       const float* __restrict__ q2c, float* __restrict__ out) {
  int t = blockIdx.x * 256 + threadIdx.x;  // B*C*H/4 = 1048576 float4s
  int h4 = t & 31;
  int bc = t >> 5;
  int b = bc >> 11;
  float4 cvv = *(const float4*)&ctx[(size_t)t * 4];
  float4 g = *(const float4*)&q2c[b * H_ + h4 * 4];
  float4 r = make_float4(cvv.x * g.x, cvv.y * g.y, cvv.z * g.z, cvv.w * g.w);
  *(float4*)&out[((size_t)bc) * (4 * H_) + 3 * H_ + h4 * 4] = r;
}

extern "C" void kernel_launch(void* const* d_in, const int* in_sizes, int n_in,
                              void* d_out, int out_size, void* d_ws,
                              size_t ws_size, hipStream_t stream) {
  const float* ctx = (const float*)d_in[0];
  const float* qry = (const float*)d_in[1];
  const float* W = (const float*)d_in[2];
  const int* cmask = (const int*)d_in[3];
  const int* qmask = (const int*)d_in[4];
  float* out = (float*)d_out;
  float* ws = (float*)d_ws;

  float* sq = ws;                      // 2048
  float* maxq = ws + 2048;             // 32768
  float* mz = ws + 2048 + B_ * C_;     // 32
  float* q2c = mz + 32;                // 2048

  k0_sq<<<8, 256, 0, stream>>>(qry, W, sq);
  k1_main<<<B_ * 32, 512, 0, stream>>>(ctx, qry, W, cmask, qmask, sq, out, maxq);
  k2_mz<<<B_, 256, 0, stream>>>(maxq, mz, q2c);
  k3_q2c<<<B_ * 16, 128, 0, stream>>>(ctx, maxq, mz, q2c);
  k4_out<<<4096, 256, 0, stream>>>(ctx, q2c, out);
}

// Round 2
// 43.289 us; speedup vs baseline: 2.0517x; 2.0517x over previous
//
#include <hip/hip_runtime.h>
#include <math.h>

#define B_ 16
#define C_ 2048
#define Q_ 128
#define H_ 128
#define NEGV (-1000000000.0f)

typedef short short8 __attribute__((ext_vector_type(8)));
typedef float f32x16 __attribute__((ext_vector_type(16)));

__device__ __forceinline__ short f2bf(float f) {
  unsigned u = __builtin_bit_cast(unsigned, f);
  u += 0x7fffu + ((u >> 16) & 1u);
  return (short)(u >> 16);
}

// swizzled short-index of 16B chunk `chunk16` in row `row` of a [128][128] bf16 tile
__device__ __forceinline__ int swz8(int row, int chunk16) {
  return row * 128 + (((chunk16 ^ (row & 7)) & 15) << 3);
}

__device__ __forceinline__ float wave_reduce_sum(float v) {
#pragma unroll
  for (int off = 32; off; off >>= 1) v += __shfl_xor(v, off, 64);
  return v;
}

// K0: s_q[b,q] = query[b,q,:] . W[H:2H]
__global__ void k0_sq(const float* __restrict__ qry, const float* __restrict__ W,
                      float* __restrict__ sq) {
  int t = blockIdx.x * 256 + threadIdx.x;
  if (t >= B_ * Q_) return;
  const float4* qp = (const float4*)(qry + (size_t)t * H_);
  const float4* wq = (const float4*)(W + H_);
  float s = 0.f;
#pragma unroll
  for (int j = 0; j < H_ / 4; j++) {
    float4 a = qp[j], w = wq[j];
    s += a.x * w.x + a.y * w.y + a.z * w.z + a.w * w.w;
  }
  sq[t] = s;
}

// K1: per (b, 128-c tile): S^T via MFMA, softmax, c2q via MFMA, G chunks 1-3, max_q.
// 512 threads = 8 waves. MFMA: v_mfma_f32_32x32x16_bf16.
__global__ __launch_bounds__(512, 1) void k1_main(
    const float* __restrict__ ctx, const float* __restrict__ qry,
    const float* __restrict__ W, const int* __restrict__ cmask,
    const int* __restrict__ qmask, const float* __restrict__ sq,
    float* __restrict__ out, float* __restrict__ maxq) {
  __shared__ short Qs[16384];   // qry[q][h] bf16, swizzled   (A of S^T)
  __shared__ short QTs[16384];  // qry^T[h][q] bf16, swizzled (B of c2q)
  __shared__ short Xs[16384];   // x[c][h] bf16, swizzled; later reused as a[c][q]
  __shared__ float scv[128];    // sc[c] = ctx_row . w_c
  __shared__ float sqm[128];    // qmask ? sq[q] : -1e12
  __shared__ float pm_lds[2][128];  // per-q-half max partials
  __shared__ float ps_lds[2][128];  // per-q-half sum partials

  int b = blockIdx.x >> 4;
  int ct = blockIdx.x & 15;
  int tid = threadIdx.x;
  int bc0 = b * C_ + ct * 128;

  // ---- stage ctx tile: chunk1 of out, sc[c], Xs ----
  {
    int c = tid >> 2, part = tid & 3;
    const float* crow = ctx + (size_t)(bc0 + c) * H_;
    float* orow = out + (size_t)(bc0 + c) * (4 * H_);
    float wsum = 0.f;
#pragma unroll
    for (int jj = 0; jj < 8; jj++) {
      int k = part + 4 * jj;  // float4 chunk 0..31
      float4 v = *(const float4*)&crow[4 * k];
      *(float4*)&orow[4 * k] = v;  // G chunk 1 = ctx (exact fp32)
      float4 wc = *(const float4*)&W[4 * k];
      float4 wq = *(const float4*)&W[2 * H_ + 4 * k];
      wsum += v.x * wc.x + v.y * wc.y + v.z * wc.z + v.w * wc.w;
      short4 xp;
      xp.x = f2bf(v.x * wq.x);
      xp.y = f2bf(v.y * wq.y);
      xp.z = f2bf(v.z * wq.z);
      xp.w = f2bf(v.w * wq.w);
      *(short4*)&Xs[swz8(c, k >> 1) + (k & 1) * 4] = xp;
    }
    wsum += __shfl_xor(wsum, 1, 64);
    wsum += __shfl_xor(wsum, 2, 64);
    if (part == 0) scv[c] = wsum;
  }
  // ---- stage qry: Qs + QTs ----
  {
    int qp = tid >> 3, p = tid & 7;
    const float* q0r = qry + (size_t)(b * Q_ + 2 * qp) * H_;
    const float* q1r = q0r + H_;
#pragma unroll
    for (int jj = 0; jj < 4; jj++) {
      int k = p + 8 * jj;  // float4 chunk 0..31
      float4 v0 = *(const float4*)&q0r[4 * k];
      float4 v1 = *(const float4*)&q1r[4 * k];
      short4 p0, p1;
      p0.x = f2bf(v0.x); p0.y = f2bf(v0.y); p0.z = f2bf(v0.z); p0.w = f2bf(v0.w);
      p1.x = f2bf(v1.x); p1.y = f2bf(v1.y); p1.z = f2bf(v1.z); p1.w = f2bf(v1.w);
      *(short4*)&Qs[swz8(2 * qp, k >> 1) + (k & 1) * 4] = p0;
      *(short4*)&Qs[swz8(2 * qp + 1, k >> 1) + (k & 1) * 4] = p1;
      const float* f0 = (const float*)&v0;
      const float* f1 = (const float*)&v1;
#pragma unroll
      for (int e = 0; e < 4; e++) {
        int h = 4 * k + e;
        short2 pr;
        pr.x = f2bf(f0[e]);
        pr.y = f2bf(f1[e]);
        *(short2*)&QTs[h * 128 + ((((qp >> 2) ^ (h & 7)) & 15) << 3) + ((2 * qp) & 7)] = pr;
      }
    }
  }
  if (tid < Q_) {
    sqm[tid] = qmask[b * Q_ + tid] ? sq[b * Q_ + tid] : -1e12f;
  }
  __syncthreads();

  int w = tid >> 6, lane = tid & 63;
  int lq = lane & 31, kg = lane >> 5;

  // ---- S^T = Q . X^T : M=q(128, 4 frags), N=c(128, 4 frags), K=h(128) ----
  // wave (wm, wn): q-block wm*64 (2 frags), c-block wn*32 (1 frag)
  int wm = w >> 2, wn = w & 3;
  f32x16 acc[2];
#pragma unroll
  for (int mf = 0; mf < 2; mf++)
#pragma unroll
    for (int r = 0; r < 16; r++) acc[mf][r] = 0.f;
  {
    int rA0 = wm * 64 + lq, rA1 = rA0 + 32, rB = wn * 32 + lq;
#pragma unroll
    for (int ks = 0; ks < 8; ks++) {
      int ch = 2 * ks + kg;
      short8 a0 = *(const short8*)&Qs[swz8(rA0, ch)];
      short8 a1 = *(const short8*)&Qs[swz8(rA1, ch)];
      short8 bb = *(const short8*)&Xs[swz8(rB, ch)];
      acc[0] = __builtin_amdgcn_mfma_f32_32x32x16_bf16(a0, bb, acc[0], 0, 0, 0);
      acc[1] = __builtin_amdgcn_mfma_f32_32x32x16_bf16(a1, bb, acc[1], 0, 0, 0);
    }
  }

  // ---- softmax over q (rows of S^T) per c (cols) ----
  int cL = wn * 32 + lq;
  float scc = scv[cL];
  float pmax = -3e38f;
#pragma unroll
  for (int mf = 0; mf < 2; mf++)
#pragma unroll
    for (int g = 0; g < 4; g++) {
      int q0 = wm * 64 + mf * 32 + 8 * g + 4 * kg;
      float4 s4 = *(const float4*)&sqm[q0];
      float sv[4] = {s4.x, s4.y, s4.z, s4.w};
#pragma unroll
      for (int r = 0; r < 4; r++) {
        float Sv = acc[mf][4 * g + r] + scc + sv[r];
        acc[mf][4 * g + r] = Sv;
        pmax = fmaxf(pmax, Sv);
      }
    }
  pmax = fmaxf(pmax, __shfl_xor(pmax, 32, 64));
  if (lane < 32) pm_lds[wm][cL] = pmax;
  __syncthreads();  // also: all MFMA reads of Xs complete

  float M = fmaxf(pm_lds[0][cL], pm_lds[1][cL]);
  if (wm == 0 && lane < 32) {
    maxq[bc0 + cL] = cmask[bc0 + cL] ? M : NEGV;
  }
  float psum = 0.f;
#pragma unroll
  for (int mf = 0; mf < 2; mf++)
#pragma unroll
    for (int g = 0; g < 4; g++) {
      int q0 = wm * 64 + mf * 32 + 8 * g + 4 * kg;
      float e0 = __expf(acc[mf][4 * g + 0] - M);
      float e1 = __expf(acc[mf][4 * g + 1] - M);
      float e2 = __expf(acc[mf][4 * g + 2] - M);
      float e3 = __expf(acc[mf][4 * g + 3] - M);
      psum += e0 + e1 + e2 + e3;
      short4 pk;
      pk.x = f2bf(e0); pk.y = f2bf(e1); pk.z = f2bf(e2); pk.w = f2bf(e3);
      // a[c][q] (unnormalized exp) into Xs
      *(short4*)&Xs[swz8(cL, q0 >> 3) + (q0 & 7)] = pk;
    }
  psum += __shfl_xor(psum, 32, 64);
  if (lane < 32) ps_lds[wm][cL] = psum;
  __syncthreads();

  // ---- c2q = a . qry : M=c(128, 4 frags), N=h(128, 4 frags), K=q(128) ----
  // wave (wm2, wn2): c-block wm2*32 (1 frag), h-block wn2*64 (2 frags)
  int wm2 = w & 3, wn2 = w >> 2;
  f32x16 o[2];
#pragma unroll
  for (int nf = 0; nf < 2; nf++)
#pragma unroll
    for (int r = 0; r < 16; r++) o[nf][r] = 0.f;
  {
    int rA = wm2 * 32 + lq;
    int rB0 = wn2 * 64 + lq, rB1 = rB0 + 32;
#pragma unroll
    for (int ks = 0; ks < 8; ks++) {
      int ch = 2 * ks + kg;
      short8 af = *(const short8*)&Xs[swz8(rA, ch)];
      short8 b0 = *(const short8*)&QTs[swz8(rB0, ch)];
      short8 b1 = *(const short8*)&QTs[swz8(rB1, ch)];
      o[0] = __builtin_amdgcn_mfma_f32_32x32x16_bf16(af, b0, o[0], 0, 0, 0);
      o[1] = __builtin_amdgcn_mfma_f32_32x32x16_bf16(af, b1, o[1], 0, 0, 0);
    }
  }

  // ---- epilogue: normalize by Z, write G chunks 2,3 ----
  int h0 = wn2 * 64 + lq, h1 = h0 + 32;
#pragma unroll
  for (int g = 0; g < 4; g++) {
    int c0 = wm2 * 32 + 8 * g + 4 * kg;
    float4 z0 = *(const float4*)&ps_lds[0][c0];
    float4 z1 = *(const float4*)&ps_lds[1][c0];
    float zz[4] = {z0.x + z1.x, z0.y + z1.y, z0.z + z1.z, z0.w + z1.w};
#pragma unroll
    for (int r = 0; r < 4; r++) {
      int c = c0 + r;
      float rz = 1.f / zz[r];
      size_t ro = (size_t)(bc0 + c) * (4 * H_);
      const float* crow = ctx + (size_t)(bc0 + c) * H_;
      float ov0 = o[0][4 * g + r] * rz;
      float ov1 = o[1][4 * g + r] * rz;
      float cv0 = crow[h0];
      float cv1 = crow[h1];
      out[ro + H_ + h0] = ov0;
      out[ro + H_ + h1] = ov1;
      out[ro + 2 * H_ + h0] = ov0 * cv0;
      out[ro + 2 * H_ + h1] = ov1 * cv1;
    }
  }
}

// K2: per-b M/Z over maxq; zero q2c
__global__ void k2_mz(const float* __restrict__ maxq, float* __restrict__ mz,
                      float* __restrict__ q2c) {
  int b = blockIdx.x;
  int tid = threadIdx.x;  // 256
  __shared__ float red[256];
  float m = -INFINITY;
  for (int c = tid; c < C_; c += 256) m = fmaxf(m, maxq[b * C_ + c]);
  red[tid] = m;
  __syncthreads();
  for (int s = 128; s; s >>= 1) {
    if (tid < s) red[tid] = fmaxf(red[tid], red[tid + s]);
    __syncthreads();
  }
  float M = red[0];
  __syncthreads();
  float z = 0.f;
  for (int c = tid; c < C_; c += 256) z += __expf(maxq[b * C_ + c] - M);
  red[tid] = z;
  __syncthreads();
  for (int s = 128; s; s >>= 1) {
    if (tid < s) red[tid] += red[tid + s];
    __syncthreads();
  }
  if (tid == 0) {
    mz[b * 2] = M;
    mz[b * 2 + 1] = red[0];
  }
  if (tid < H_) q2c[b * H_ + tid] = 0.f;
}

// K3: q2c[b,:] += sum_c softmax_c(maxq)[c] * ctx[b,c,:]  (256 blocks x 256 thr)
__global__ void k3_q2c(const float* __restrict__ ctx,
                       const float* __restrict__ maxq,
                       const float* __restrict__ mz, float* __restrict__ q2c) {
  __shared__ float4 red[256];
  int b = blockIdx.x >> 4, chunk = blockIdx.x & 15;
  int tid = threadIdx.x;
  int h4 = tid & 31, cl = tid >> 5;
  float M = mz[2 * b], Z = mz[2 * b + 1];
  float4 acc = {0.f, 0.f, 0.f, 0.f};
  int cbase = chunk * 128 + cl * 16;
#pragma unroll
  for (int i = 0; i < 16; i++) {
    int c = cbase + i;
    float wgt = __expf(maxq[b * C_ + c] - M);
    float4 v = *(const float4*)&ctx[(size_t)(b * C_ + c) * H_ + 4 * h4];
    acc.x += wgt * v.x;
    acc.y += wgt * v.y;
    acc.z += wgt * v.z;
    acc.w += wgt * v.w;
  }
  red[tid] = acc;
  __syncthreads();
  for (int s = 4; s; s >>= 1) {
    if (cl < s) {
      float4 o2 = red[(cl + s) * 32 + h4];
      acc.x += o2.x; acc.y += o2.y; acc.z += o2.z; acc.w += o2.w;
      red[tid] = acc;
    }
    __syncthreads();
  }
  if (cl == 0) {
    float rzz = 1.f / Z;
    atomicAdd(&q2c[b * H_ + 4 * h4 + 0], acc.x * rzz);
    atomicAdd(&q2c[b * H_ + 4 * h4 + 1], acc.y * rzz);
    atomicAdd(&q2c[b * H_ + 4 * h4 + 2], acc.z * rzz);
    atomicAdd(&q2c[b * H_ + 4 * h4 + 3], acc.w * rzz);
  }
}

// K4: G chunk 4 = ctx * q2c (broadcast over c)
__global__ void k4_out(const float* __restrict__ ctx,
                       const float* __restrict__ q2c, float* __restrict__ out) {
  int t = blockIdx.x * 256 + threadIdx.x;  // B*C*H/4 float4s
  int h4 = t & 31;
  int bc = t >> 5;
  int b = bc >> 11;
  float4 cvv = *(const float4*)&ctx[(size_t)t * 4];
  float4 g = *(const float4*)&q2c[b * H_ + h4 * 4];
  float4 r = make_float4(cvv.x * g.x, cvv.y * g.y, cvv.z * g.z, cvv.w * g.w);
  *(float4*)&out[((size_t)bc) * (4 * H_) + 3 * H_ + h4 * 4] = r;
}

extern "C" void kernel_launch(void* const* d_in, const int* in_sizes, int n_in,
                              void* d_out, int out_size, void* d_ws,
                              size_t ws_size, hipStream_t stream) {
  const float* ctx = (const float*)d_in[0];
  const float* qry = (const float*)d_in[1];
  const float* W = (const float*)d_in[2];
  const int* cmask = (const int*)d_in[3];
  const int* qmask = (const int*)d_in[4];
  float* out = (float*)d_out;
  float* ws = (float*)d_ws;

  float* sq = ws;                   // 2048
  float* maxq = ws + 2048;          // 32768
  float* mz = ws + 2048 + B_ * C_;  // 32
  float* q2c = mz + 32;             // 2048

  k0_sq<<<8, 256, 0, stream>>>(qry, W, sq);
  k1_main<<<B_ * 16, 512, 0, stream>>>(ctx, qry, W, cmask, qmask, sq, out, maxq);
  k2_mz<<<B_, 256, 0, stream>>>(maxq, mz, q2c);
  k3_q2c<<<B_ * 16, 256, 0, stream>>>(ctx, maxq, mz, q2c);
  k4_out<<<4096, 256, 0, stream>>>(ctx, q2c, out);
}